// Round 1
// baseline (212.126 us; speedup 1.0000x reference)
//
#include <hip/hip_runtime.h>
#include <hip/hip_bf16.h>

#define HWs   16384
#define Wimg  128
#define Himg  128
#define Cin   256
#define Oout  256
#define CKd   2304
#define Bb    2

typedef short   bf16x8 __attribute__((ext_vector_type(8)));
typedef float   f32x4  __attribute__((ext_vector_type(4)));

__device__ __forceinline__ float bf2f(ushort u){
  union { unsigned int i; float f; } v; v.i = ((unsigned int)u) << 16; return v.f;
}
__device__ __forceinline__ ushort f2bf(float f){
  union { float f; unsigned int i; } v; v.f = f;
  unsigned int r = v.i + 0x7FFFu + ((v.i >> 16) & 1u);
  return (ushort)(r >> 16);
}

// ---------------- x [B,C,H,W] fp32 -> x_t [B,HW,C] bf16 ----------------
__global__ __launch_bounds__(256) void k_transpose(const float* __restrict__ x,
                                                   ushort* __restrict__ xt){
  int bx = blockIdx.x;                 // B * 4 * 256
  int b  = bx >> 10;
  int r  = bx & 1023;
  int ct = r >> 8;                     // c-tile (64 each)
  int pt = r & 255;                    // pix-tile (64 each)
  int c0 = ct * 64, p0 = pt * 64;
  __shared__ float tile[64][65];
  const float* xb = x + (size_t)b * Cin * HWs;
  #pragma unroll
  for (int pass = 0; pass < 16; ++pass){
    int idx = pass * 256 + threadIdx.x;
    int cl = idx >> 6, pl = idx & 63;
    tile[cl][pl] = xb[(size_t)(c0 + cl) * HWs + p0 + pl];
  }
  __syncthreads();
  ushort* xo = xt + (size_t)b * HWs * Cin;
  #pragma unroll
  for (int pass = 0; pass < 16; ++pass){
    int idx = pass * 256 + threadIdx.x;
    int pl = idx >> 6, cl = idx & 63;
    xo[(size_t)(p0 + pl) * Cin + c0 + cl] = f2bf(tile[cl][pl]);
  }
}

// ---------------- w [O,C,9] fp32 -> w2 [O][k*256+c] bf16 (k-major) ----------------
__global__ __launch_bounds__(256) void k_wconv(const float* __restrict__ w,
                                               ushort* __restrict__ w2){
  int idx = blockIdx.x * 256 + threadIdx.x;    // 256*2304
  int o = idx / CKd, r = idx % CKd;
  int k = r >> 8, c = r & 255;
  w2[idx] = f2bf(w[(size_t)(o * Cin + c) * 9 + k]);
}

// ---------------- w_off [18,C,9] fp32 -> w2of [32][k*256+c] bf16, rows 18..31 zero ----------------
__global__ __launch_bounds__(256) void k_wofconv(const float* __restrict__ wof,
                                                 ushort* __restrict__ w2of){
  int idx = blockIdx.x * 256 + threadIdx.x;    // 32*2304
  int o = idx / CKd, r = idx % CKd;
  int k = r >> 8, c = r & 255;
  float v = (o < 18) ? wof[(size_t)(o * Cin + c) * 9 + k] : 0.f;
  w2of[idx] = f2bf(v);
}

// ---------------- offset conv as M=32 MFMA GEMM: offs[b][18][hw] fp32 ----------------
__global__ __launch_bounds__(512) void k_offconv(const ushort* __restrict__ xt,
                                                 const ushort* __restrict__ w2of,
                                                 const float* __restrict__ b_off,
                                                 float* __restrict__ offs){
  int bx = blockIdx.x;                          // 256
  int m  = ((bx & 7) << 5) | (bx >> 3);         // XCD-chunked swizzle (bijective, 256%8==0)
  int b = m >> 7, tile = m & 127;
  int hw0 = tile * 128;                         // one full image row
  int i_row = tile;
  __shared__ __align__(16) ushort wl[32 * 64];
  __shared__ __align__(16) ushort vl[128 * 64];
  int t = threadIdx.x, lane = t & 63, wid = t >> 6;
  f32x4 acc[2];
  acc[0] = (f32x4){0,0,0,0}; acc[1] = (f32x4){0,0,0,0};
  const ushort* xb = xt + (size_t)b * HWs * Cin;

  for (int step = 0; step < 36; ++step){
    int kk = step * 64, k = kk >> 8, c0 = kk & 255;
    int dy = k / 3 - 1, dx = k % 3 - 1;
    __syncthreads();
    if (t < 256){                               // stage A: 32x64
      int o = t >> 3, cg = t & 7;
      bf16x8 wv = *(const bf16x8*)(w2of + (size_t)o * CKd + kk + cg * 8);
      int byte = o * 128 + cg * 16; byte ^= ((o & 7) << 4);
      *(bf16x8*)((char*)wl + byte) = wv;
    }
    {                                           // stage B: shifted x_t rows, 128x64
      int cg = t & 7, hl = t >> 3;
      #pragma unroll
      for (int hh = 0; hh < 2; ++hh){
        int hw_l = hl + hh * 64;
        int ii = i_row + dy, jj = hw_l + dx;
        bf16x8 v; 
        #pragma unroll
        for (int q = 0; q < 8; ++q) v[q] = 0;
        if ((unsigned)ii < 128u && (unsigned)jj < 128u){
          int hw_src = ii * 128 + jj;
          v = *(const bf16x8*)(xb + (size_t)hw_src * Cin + c0 + cg * 8);
        }
        int byte = hw_l * 128 + cg * 16; byte ^= ((hw_l & 7) << 4);
        *(bf16x8*)((char*)vl + byte) = v;
      }
    }
    __syncthreads();
    #pragma unroll
    for (int kk2 = 0; kk2 < 2; ++kk2){
      int coff = kk2 * 64 + ((lane >> 4) << 4);
      bf16x8 a0, a1, bv;
      { int r = (lane & 15);          int byte = r * 128 + coff; byte ^= ((r & 7) << 4); a0 = *(const bf16x8*)((char*)wl + byte); }
      { int r = 16 + (lane & 15);     int byte = r * 128 + coff; byte ^= ((r & 7) << 4); a1 = *(const bf16x8*)((char*)wl + byte); }
      { int r = wid * 16 + (lane & 15); int byte = r * 128 + coff; byte ^= ((r & 7) << 4); bv = *(const bf16x8*)((char*)vl + byte); }
      acc[0] = __builtin_amdgcn_mfma_f32_16x16x32_bf16(a0, bv, acc[0], 0, 0, 0);
      acc[1] = __builtin_amdgcn_mfma_f32_16x16x32_bf16(a1, bv, acc[1], 0, 0, 0);
    }
  }
  int hw = hw0 + wid * 16 + (lane & 15);
  #pragma unroll
  for (int mi = 0; mi < 2; ++mi){
    #pragma unroll
    for (int r = 0; r < 4; ++r){
      int o = mi * 16 + ((lane >> 4) << 2) + r;
      if (o < 18)
        offs[((size_t)b * 18 + o) * HWs + hw] = acc[mi][r] + b_off[o];
    }
  }
}

// ---------------- prep: per (b,k,hw) corner indices + masked bilinear weights ----------------
__global__ __launch_bounds__(256) void k_prep(const float* __restrict__ offs,
                                              int4* __restrict__ pidx,
                                              float4* __restrict__ pw){
  int e = blockIdx.x * 256 + threadIdx.x;       // B*9*HW
  int b = e / (9 * HWs); int r = e % (9 * HWs);
  int k = r / HWs; int hw = r % HWs;
  int i = hw >> 7, j = hw & 127;
  float offy = offs[((size_t)b * 18 + 2 * k) * HWs + hw];
  float offx = offs[((size_t)b * 18 + 2 * k + 1) * HWs + hw];
  float py = (float)i + (float)(k / 3 - 1) + offy;
  float px = (float)j + (float)(k % 3 - 1) + offx;
  float y0f = floorf(py), x0f = floorf(px);
  float ly = py - y0f, lx = px - x0f;
  int y0 = (int)y0f, x0 = (int)x0f;
  int y1 = y0 + 1, x1 = x0 + 1;
  float w00 = (1.f - ly) * (1.f - lx), w01 = (1.f - ly) * lx;
  float w10 = ly * (1.f - lx),         w11 = ly * lx;
  bool vy0 = (y0 >= 0 && y0 < 128), vy1 = (y1 >= 0 && y1 < 128);
  bool vx0 = (x0 >= 0 && x0 < 128), vx1 = (x1 >= 0 && x1 < 128);
  int iy0 = min(max(y0, 0), 127), iy1 = min(max(y1, 0), 127);
  int ix0 = min(max(x0, 0), 127), ix1 = min(max(x1, 0), 127);
  pidx[e] = make_int4(iy0 * 128 + ix0, iy0 * 128 + ix1, iy1 * 128 + ix0, iy1 * 128 + ix1);
  pw[e]   = make_float4(vy0 && vx0 ? w00 : 0.f, vy0 && vx1 ? w01 : 0.f,
                        vy1 && vx0 ? w10 : 0.f, vy1 && vx1 ? w11 : 0.f);
}

// ---------------- fused gather + main GEMM: out[b][o][hw] fp32 (raw, pre-BN) ----------------
__global__ __launch_bounds__(512) void k_main(const ushort* __restrict__ xt,
                                              const ushort* __restrict__ w2,
                                              const int4* __restrict__ pidx,
                                              const float4* __restrict__ pw,
                                              float* __restrict__ out){
  int bx = blockIdx.x;                          // 256
  int m  = ((bx & 7) << 5) | (bx >> 3);         // XCD-chunked swizzle
  int b = m >> 7, tile = m & 127;
  int hw0 = tile * 128;
  __shared__ __align__(16) ushort wl[256 * 64]; // 32KB swizzled
  __shared__ __align__(16) ushort vl[128 * 64]; // 16KB swizzled
  int t = threadIdx.x, lane = t & 63, wid = t >> 6;
  int wm = wid >> 1, wn = wid & 1;              // 4 x 2 wave grid (64o x 64hw each)
  f32x4 acc[4][4];
  #pragma unroll
  for (int mi = 0; mi < 4; ++mi)
    #pragma unroll
    for (int ni = 0; ni < 4; ++ni) acc[mi][ni] = (f32x4){0,0,0,0};
  const ushort* xb  = xt   + (size_t)b * HWs * Cin;
  const int4*   pib = pidx + (size_t)b * 9 * HWs;
  const float4* pwb = pw   + (size_t)b * 9 * HWs;

  for (int step = 0; step < 36; ++step){
    int kk = step * 64, k = kk >> 8, c0 = kk & 255;
    __syncthreads();
    #pragma unroll
    for (int p = 0; p < 4; ++p){                // stage A: 256x64
      int o = p * 64 + (t >> 3), cg = t & 7;
      bf16x8 wv = *(const bf16x8*)(w2 + (size_t)o * CKd + kk + cg * 8);
      int byte = o * 128 + cg * 16; byte ^= ((o & 7) << 4);
      *(bf16x8*)((char*)wl + byte) = wv;
    }
    {                                           // stage B: bilinear gather 128x64
      int cg = t & 7, hl = t >> 3;
      #pragma unroll
      for (int hh = 0; hh < 2; ++hh){
        int hw_l = hl + hh * 64;
        int hw = hw0 + hw_l;
        int4   id = pib[(size_t)k * HWs + hw];
        float4 wt = pwb[(size_t)k * HWs + hw];
        int cbase = c0 + cg * 8;
        bf16x8 c00 = *(const bf16x8*)(xb + (size_t)id.x * Cin + cbase);
        bf16x8 c01 = *(const bf16x8*)(xb + (size_t)id.y * Cin + cbase);
        bf16x8 c10 = *(const bf16x8*)(xb + (size_t)id.z * Cin + cbase);
        bf16x8 c11 = *(const bf16x8*)(xb + (size_t)id.w * Cin + cbase);
        bf16x8 vv;
        #pragma unroll
        for (int jx = 0; jx < 8; ++jx){
          float f = wt.x * bf2f((ushort)c00[jx]) + wt.y * bf2f((ushort)c01[jx])
                  + wt.z * bf2f((ushort)c10[jx]) + wt.w * bf2f((ushort)c11[jx]);
          vv[jx] = (short)f2bf(f);
        }
        int byte = hw_l * 128 + cg * 16; byte ^= ((hw_l & 7) << 4);
        *(bf16x8*)((char*)vl + byte) = vv;
      }
    }
    __syncthreads();
    #pragma unroll
    for (int kk2 = 0; kk2 < 2; ++kk2){
      int coff = kk2 * 64 + ((lane >> 4) << 4);
      bf16x8 a[4], bv[4];
      #pragma unroll
      for (int mi = 0; mi < 4; ++mi){
        int r = wm * 64 + mi * 16 + (lane & 15);
        int byte = r * 128 + coff; byte ^= ((r & 7) << 4);
        a[mi] = *(const bf16x8*)((char*)wl + byte);
      }
      #pragma unroll
      for (int ni = 0; ni < 4; ++ni){
        int r = wn * 64 + ni * 16 + (lane & 15);
        int byte = r * 128 + coff; byte ^= ((r & 7) << 4);
        bv[ni] = *(const bf16x8*)((char*)vl + byte);
      }
      #pragma unroll
      for (int mi = 0; mi < 4; ++mi)
        #pragma unroll
        for (int ni = 0; ni < 4; ++ni)
          acc[mi][ni] = __builtin_amdgcn_mfma_f32_16x16x32_bf16(a[mi], bv[ni], acc[mi][ni], 0, 0, 0);
    }
  }
  #pragma unroll
  for (int mi = 0; mi < 4; ++mi){
    int obase = wm * 64 + mi * 16 + ((lane >> 4) << 2);
    #pragma unroll
    for (int ni = 0; ni < 4; ++ni){
      int hw = hw0 + wn * 64 + ni * 16 + (lane & 15);
      float* op = out + ((size_t)b * Oout + obase) * HWs + hw;
      #pragma unroll
      for (int r = 0; r < 4; ++r) op[(size_t)r * HWs] = acc[mi][ni][r];
    }
  }
}

// ---------------- BN batch stats per output channel ----------------
__global__ __launch_bounds__(256) void k_bnstats(const float* __restrict__ out,
                                                 float* __restrict__ stats){
  int o = blockIdx.x, t = threadIdx.x;
  float s = 0.f, s2 = 0.f;
  for (int b = 0; b < Bb; ++b){
    const float* p = out + ((size_t)b * Oout + o) * HWs;
    for (int i = t; i < HWs; i += 256){ float v = p[i]; s += v; s2 += v * v; }
  }
  #pragma unroll
  for (int off = 32; off > 0; off >>= 1){
    s  += __shfl_down(s, off);
    s2 += __shfl_down(s2, off);
  }
  __shared__ float rs[4], rs2[4];
  int lane = t & 63, w = t >> 6;
  if (lane == 0){ rs[w] = s; rs2[w] = s2; }
  __syncthreads();
  if (t == 0){
    float S = 0.f, S2 = 0.f;
    for (int i = 0; i < 4; ++i){ S += rs[i]; S2 += rs2[i]; }
    float mean = S / 32768.f;
    float var  = S2 / 32768.f - mean * mean;
    stats[o] = mean;
    stats[256 + o] = rsqrtf(var + 1e-5f);
  }
}

// ---------------- normalize + ReLU in place ----------------
__global__ __launch_bounds__(256) void k_bnapply(float* __restrict__ out,
                                                 const float* __restrict__ stats,
                                                 const float* __restrict__ gamma,
                                                 const float* __restrict__ beta){
  size_t e = ((size_t)blockIdx.x * 256 + threadIdx.x) * 4;
  int o = (int)((e >> 14) & 255);
  float mean = stats[o], rstd = stats[256 + o];
  float sc = rstd * gamma[o];
  float sh = beta[o] - mean * sc;
  float4 v = *(float4*)(out + e);
  v.x = fmaxf(v.x * sc + sh, 0.f);
  v.y = fmaxf(v.y * sc + sh, 0.f);
  v.z = fmaxf(v.z * sc + sh, 0.f);
  v.w = fmaxf(v.w * sc + sh, 0.f);
  *(float4*)(out + e) = v;
}

extern "C" void kernel_launch(void* const* d_in, const int* in_sizes, int n_in,
                              void* d_out, int out_size, void* d_ws, size_t ws_size,
                              hipStream_t stream){
  const float* x     = (const float*)d_in[0];
  const float* w_off = (const float*)d_in[1];
  const float* b_off = (const float*)d_in[2];
  const float* w     = (const float*)d_in[3];
  const float* gamma = (const float*)d_in[4];
  const float* beta  = (const float*)d_in[5];
  float* out = (float*)d_out;

  char* p = (char*)d_ws;
  ushort* xt   = (ushort*)p; p += (size_t)Bb * HWs * Cin * 2;     // 16.78 MB
  ushort* w2   = (ushort*)p; p += (size_t)Oout * CKd * 2;         // 1.18 MB
  ushort* w2of = (ushort*)p; p += (size_t)32 * CKd * 2;           // 0.15 MB
  float*  offs = (float*)p;  p += (size_t)Bb * 18 * HWs * 4;      // 2.36 MB
  int4*   pidx = (int4*)p;   p += (size_t)Bb * 9 * HWs * 16;      // 4.72 MB
  float4* pwt  = (float4*)p; p += (size_t)Bb * 9 * HWs * 16;      // 4.72 MB
  float*  stats= (float*)p;                                        // 2 KB

  k_transpose<<<dim3(2048), dim3(256), 0, stream>>>(x, xt);
  k_wconv    <<<dim3(2304), dim3(256), 0, stream>>>(w, w2);
  k_wofconv  <<<dim3(288),  dim3(256), 0, stream>>>(w_off, w2of);
  k_offconv  <<<dim3(256),  dim3(512), 0, stream>>>(xt, w2of, b_off, offs);
  k_prep     <<<dim3(1152), dim3(256), 0, stream>>>(offs, pidx, pwt);
  k_main     <<<dim3(256),  dim3(512), 0, stream>>>(xt, w2, pidx, pwt, out);
  k_bnstats  <<<dim3(256),  dim3(256), 0, stream>>>(out, stats);
  k_bnapply  <<<dim3(8192), dim3(256), 0, stream>>>(out, stats, gamma, beta);
}

// Round 2
// 131.435 us; speedup vs baseline: 1.6139x; 1.6139x over previous
//
#include <hip/hip_runtime.h>
#include <hip/hip_bf16.h>

#define HWs   16384
#define Wimg  128
#define Himg  128
#define PW    130
#define PHW   16900      // 130*130 padded pixels
#define Cin   256
#define Oout  256
#define CKd   2304
#define Bb    2

typedef short   bf16x8 __attribute__((ext_vector_type(8)));
typedef float   f32x4  __attribute__((ext_vector_type(4)));

__device__ __forceinline__ float bf2f(ushort u){
  union { unsigned int i; float f; } v; v.i = ((unsigned int)u) << 16; return v.f;
}
__device__ __forceinline__ ushort f2bf(float f){
  union { float f; unsigned int i; } v; v.f = f;
  unsigned int r = v.i + 0x7FFFu + ((v.i >> 16) & 1u);
  return (ushort)(r >> 16);
}
__device__ __forceinline__ void gload_lds16(const ushort* g, void* l){
  __builtin_amdgcn_global_load_lds(
      (const __attribute__((address_space(1))) unsigned int*)g,
      (__attribute__((address_space(3))) unsigned int*)l, 16, 0, 0);
}

// ---------------- x [B,C,H,W] fp32 -> xtp [B][130*130][C] bf16 (interior) ----------------
__global__ __launch_bounds__(256) void k_transpose(const float* __restrict__ x,
                                                   ushort* __restrict__ xtp){
  int bx = blockIdx.x;                 // B * 4 * 256 = 2048
  int b  = bx >> 10;
  int r  = bx & 1023;
  int ct = r >> 8;                     // c-tile (64 each)
  int pt = r & 255;                    // pix-tile (64 each)
  int c0 = ct * 64, p0 = pt * 64;
  __shared__ float tile[64][65];
  const float* xb = x + (size_t)b * Cin * HWs;
  #pragma unroll
  for (int pass = 0; pass < 16; ++pass){
    int idx = pass * 256 + threadIdx.x;
    int cl = idx >> 6, pl = idx & 63;
    tile[cl][pl] = xb[(size_t)(c0 + cl) * HWs + p0 + pl];
  }
  __syncthreads();
  ushort* xo = xtp + (size_t)b * PHW * Cin;
  #pragma unroll
  for (int pass = 0; pass < 16; ++pass){
    int idx = pass * 256 + threadIdx.x;
    int pl = idx >> 6, cl = idx & 63;
    int hw = p0 + pl; int y = hw >> 7, xc = hw & 127;
    xo[(size_t)((y + 1) * PW + xc + 1) * Cin + c0 + cl] = f2bf(tile[cl][pl]);
  }
}

// ---------------- zero the padded border ----------------
__global__ __launch_bounds__(64) void k_border(ushort* __restrict__ xtp){
  int e = blockIdx.x;                  // 2 * 516
  int b = e / 516, p = e % 516;
  int y, xc;
  if (p < 130)      { y = 0;       xc = p; }
  else if (p < 260) { y = 129;     xc = p - 130; }
  else if (p < 388) { y = p - 259; xc = 0; }
  else              { y = p - 387; xc = 129; }
  uint2* dst = (uint2*)(xtp + ((size_t)b * PHW + y * PW + xc) * Cin) + threadIdx.x;
  *dst = make_uint2(0u, 0u);
}

// ---------------- weights -> k-major bf16: w2 [256][2304], w2of [32][2304] ----------------
__global__ __launch_bounds__(256) void k_wprep(const float* __restrict__ w,
                                               const float* __restrict__ wof,
                                               ushort* __restrict__ w2,
                                               ushort* __restrict__ w2of){
  int idx = blockIdx.x * 256 + threadIdx.x;    // 2592*256 = 256*2304 + 32*2304
  if (idx < Oout * CKd){
    int o = idx / CKd, r = idx % CKd;
    int k = r >> 8, c = r & 255;
    w2[idx] = f2bf(w[(size_t)(o * Cin + c) * 9 + k]);
  } else {
    int j = idx - Oout * CKd;
    int o = j / CKd, r = j % CKd;
    int k = r >> 8, c = r & 255;
    float v = (o < 18) ? wof[(size_t)(o * Cin + c) * 9 + k] : 0.f;
    w2of[j] = f2bf(v);
  }
}

// ---------------- offset conv (M=32 MFMA) + fused prep: pidx/pw (padded indices) ----------------
__global__ __launch_bounds__(512) void k_offconv(const ushort* __restrict__ xtp,
                                                 const ushort* __restrict__ w2of,
                                                 const float* __restrict__ b_off,
                                                 int4* __restrict__ pidx,
                                                 float4* __restrict__ pw){
  int bx = blockIdx.x;                          // 256
  int blkm = ((bx & 7) << 5) | (bx >> 3);       // XCD-chunked swizzle
  int b = blkm >> 7, tile = blkm & 127;         // tile = image row
  int hw0 = tile * 128;
  __shared__ __align__(16) ushort wl[32 * 64];   // 4KB
  __shared__ __align__(16) ushort vl[128 * 64];  // 16KB
  __shared__ float offs_lds[18][128];            // 9KB
  int t = threadIdx.x, lane = t & 63, wid = t >> 6;
  f32x4 acc[2];
  acc[0] = (f32x4){0,0,0,0}; acc[1] = (f32x4){0,0,0,0};
  const ushort* xb = xtp + (size_t)b * PHW * Cin;

  #pragma unroll 1
  for (int step = 0; step < 36; ++step){
    int kk = step * 64, k = kk >> 8, c0 = kk & 255;
    int dy = k / 3 - 1, dx = k % 3 - 1;
    __syncthreads();
    if (wid < 4){                                // stage A: 32x64 via gload_lds (swizzled src)
      int L = wid * 1024 + lane * 16;
      int oo = L >> 7; int inb = (L & 127) ^ ((oo & 7) << 4);
      gload_lds16(w2of + (size_t)oo * CKd + kk + (inb >> 1), (char*)wl + L);
    }
    #pragma unroll
    for (int h = 0; h < 2; ++h){                 // stage B: 128x64 shifted padded rows
      int L = (wid * 2 + h) * 1024 + lane * 16;
      int hw_l = L >> 7; int inb = (L & 127) ^ ((hw_l & 7) << 4);
      int row = (tile + dy + 1) * PW + (hw_l + dx + 1);
      gload_lds16(xb + (size_t)row * Cin + c0 + (inb >> 1), (char*)vl + L);
    }
    __syncthreads();
    #pragma unroll
    for (int kk2 = 0; kk2 < 2; ++kk2){
      int coff = kk2 * 64 + ((lane >> 4) << 4);
      bf16x8 a0, a1, bv;
      { int r = (lane & 15);            int byte = r * 128 + coff; byte ^= ((r & 7) << 4); a0 = *(const bf16x8*)((char*)wl + byte); }
      { int r = 16 + (lane & 15);       int byte = r * 128 + coff; byte ^= ((r & 7) << 4); a1 = *(const bf16x8*)((char*)wl + byte); }
      { int r = wid * 16 + (lane & 15); int byte = r * 128 + coff; byte ^= ((r & 7) << 4); bv = *(const bf16x8*)((char*)vl + byte); }
      acc[0] = __builtin_amdgcn_mfma_f32_16x16x32_bf16(a0, bv, acc[0], 0, 0, 0);
      acc[1] = __builtin_amdgcn_mfma_f32_16x16x32_bf16(a1, bv, acc[1], 0, 0, 0);
    }
  }
  // epilogue: offsets -> LDS
  int hwl = wid * 16 + (lane & 15);
  #pragma unroll
  for (int mi = 0; mi < 2; ++mi){
    #pragma unroll
    for (int r = 0; r < 4; ++r){
      int o = mi * 16 + ((lane >> 4) << 2) + r;
      if (o < 18) offs_lds[o][hwl] = acc[mi][r] + b_off[o];
    }
  }
  __syncthreads();
  // fused prep: 9 taps x 128 hw
  for (int idx = t; idx < 9 * 128; idx += 512){
    int k = idx >> 7, j = idx & 127;
    float offy = offs_lds[2 * k][j];
    float offx = offs_lds[2 * k + 1][j];
    float py = (float)tile + (float)(k / 3 - 1) + offy;
    float px = (float)j    + (float)(k % 3 - 1) + offx;
    float y0f = floorf(py), x0f = floorf(px);
    float ly = py - y0f, lx = px - x0f;
    int y0 = (int)y0f, x0 = (int)x0f;
    int y1 = y0 + 1, x1 = x0 + 1;
    float w00 = (1.f - ly) * (1.f - lx), w01 = (1.f - ly) * lx;
    float w10 = ly * (1.f - lx),         w11 = ly * lx;
    bool vy0 = (y0 >= 0 && y0 < 128), vy1 = (y1 >= 0 && y1 < 128);
    bool vx0 = (x0 >= 0 && x0 < 128), vx1 = (x1 >= 0 && x1 < 128);
    int iy0 = min(max(y0, 0), 127), iy1 = min(max(y1, 0), 127);
    int ix0 = min(max(x0, 0), 127), ix1 = min(max(x1, 0), 127);
    size_t e = ((size_t)b * 9 + k) * HWs + hw0 + j;
    pidx[e] = make_int4((iy0 + 1) * PW + ix0 + 1, (iy0 + 1) * PW + ix1 + 1,
                        (iy1 + 1) * PW + ix0 + 1, (iy1 + 1) * PW + ix1 + 1);
    pw[e]   = make_float4(vy0 && vx0 ? w00 : 0.f, vy0 && vx1 ? w01 : 0.f,
                          vy1 && vx0 ? w10 : 0.f, vy1 && vx1 ? w11 : 0.f);
  }
}

// ---------------- fused gather + main GEMM, double-buffered 1-barrier pipeline ----------------
__device__ __forceinline__ void mfma_phase(const ushort* Ab, const ushort* Bbp,
                                           int lane, int wm, int wn, f32x4 (&acc)[4][4]){
  #pragma unroll
  for (int kk2 = 0; kk2 < 2; ++kk2){
    int coff = kk2 * 64 + ((lane >> 4) << 4);
    bf16x8 a[4], bv[4];
    #pragma unroll
    for (int mi = 0; mi < 4; ++mi){
      int r = wm * 64 + mi * 16 + (lane & 15);
      int byte = r * 128 + coff; byte ^= ((r & 7) << 4);
      a[mi] = *(const bf16x8*)((const char*)Ab + byte);
    }
    #pragma unroll
    for (int ni = 0; ni < 4; ++ni){
      int r = wn * 64 + ni * 16 + (lane & 15);
      int byte = r * 128 + coff; byte ^= ((r & 7) << 4);
      bv[ni] = *(const bf16x8*)((const char*)Bbp + byte);
    }
    #pragma unroll
    for (int mi = 0; mi < 4; ++mi)
      #pragma unroll
      for (int ni = 0; ni < 4; ++ni)
        acc[mi][ni] = __builtin_amdgcn_mfma_f32_16x16x32_bf16(a[mi], bv[ni], acc[mi][ni], 0, 0, 0);
  }
}

__global__ __launch_bounds__(512, 2) void k_main(const ushort* __restrict__ xtp,
                                                 const ushort* __restrict__ w2,
                                                 const int4* __restrict__ pidx,
                                                 const float4* __restrict__ pw,
                                                 float* __restrict__ out,
                                                 float* __restrict__ partials){
  int bx = blockIdx.x;                          // 256
  int blkm = ((bx & 7) << 5) | (bx >> 3);       // XCD-chunked swizzle
  int b = blkm >> 7, tile = blkm & 127;
  int hw0 = tile * 128;
  __shared__ __align__(16) ushort smem[49152];  // 96KB: A dbuf 2x32KB, B dbuf 2x16KB
  ushort* Ab0 = smem;
  ushort* Ab1 = smem + 16384;
  ushort* Bb0 = smem + 32768;
  ushort* Bb1 = smem + 40960;
  int t = threadIdx.x, lane = t & 63, wid = t >> 6;
  int wm = wid >> 1, wn = wid & 1;
  int cg = t & 7, hl = t >> 3;                  // B staging coords: c-group, hw-lane
  f32x4 acc[4][4];
  #pragma unroll
  for (int mi = 0; mi < 4; ++mi)
    #pragma unroll
    for (int ni = 0; ni < 4; ++ni) acc[mi][ni] = (f32x4){0,0,0,0};
  const ushort* xb  = xtp  + (size_t)b * PHW * Cin;
  const int4*   pib = pidx + (size_t)b * 9 * HWs + hw0;
  const float4* pwb = pw   + (size_t)b * 9 * HWs + hw0;

  int4   ids[2][2];
  float4 wts[2][2];
  bf16x8 g[2][4];

#define IDXLOAD(P, S) \
  if ((S) < 36){ int kq = (S) >> 2; \
    ids[P][0] = pib[(size_t)kq * HWs + hl];       wts[P][0] = pwb[(size_t)kq * HWs + hl]; \
    ids[P][1] = pib[(size_t)kq * HWs + hl + 64];  wts[P][1] = pwb[(size_t)kq * HWs + hl + 64]; }

#define CORNERS(P, S) \
  if ((S) < 36){ int cb = (((S) * 64) & 255) + cg * 8; \
    _Pragma("unroll") for (int hh = 0; hh < 2; ++hh){ \
      g[hh][0] = *(const bf16x8*)(xb + (size_t)ids[P][hh].x * Cin + cb); \
      g[hh][1] = *(const bf16x8*)(xb + (size_t)ids[P][hh].y * Cin + cb); \
      g[hh][2] = *(const bf16x8*)(xb + (size_t)ids[P][hh].z * Cin + cb); \
      g[hh][3] = *(const bf16x8*)(xb + (size_t)ids[P][hh].w * Cin + cb); } }

#define STAGEA(S, ABP) \
  if ((S) < 36){ int kks = (S) * 64; \
    _Pragma("unroll") for (int h2 = 0; h2 < 4; ++h2){ \
      int L = (wid * 4 + h2) * 1024 + lane * 16; \
      int oo = L >> 7; int inb = (L & 127) ^ ((oo & 7) << 4); \
      gload_lds16(w2 + (size_t)oo * CKd + kks + (inb >> 1), (char*)(ABP) + L); } }

#define COMBINE(P, S, BBP) \
  if ((S) < 36){ \
    _Pragma("unroll") for (int hh = 0; hh < 2; ++hh){ \
      int hw_l = hl + hh * 64; \
      float4 wtv = wts[P][hh]; \
      bf16x8 vv; \
      _Pragma("unroll") for (int jx = 0; jx < 8; ++jx){ \
        float f = wtv.x * bf2f((ushort)g[hh][0][jx]) + wtv.y * bf2f((ushort)g[hh][1][jx]) \
                + wtv.z * bf2f((ushort)g[hh][2][jx]) + wtv.w * bf2f((ushort)g[hh][3][jx]); \
        vv[jx] = (short)f2bf(f); } \
      int byte = hw_l * 128 + cg * 16; byte ^= ((hw_l & 7) << 4); \
      *(bf16x8*)((char*)(BBP) + byte) = vv; } }

  // prologue: step 0 into buf0
  IDXLOAD(0, 0);
  IDXLOAD(1, 1);
  CORNERS(0, 0);
  STAGEA(0, Ab0);
  COMBINE(0, 0, Bb0);
  __syncthreads();

  #pragma unroll 1
  for (int tt = 0; tt < 36; tt += 2){
    // even: compute buf0, stage buf1
    IDXLOAD(0, tt + 2);
    CORNERS(1, tt + 1);
    STAGEA(tt + 1, Ab1);
    mfma_phase(Ab0, Bb0, lane, wm, wn, acc);
    COMBINE(1, tt + 1, Bb1);
    __syncthreads();
    // odd: compute buf1, stage buf0
    IDXLOAD(1, tt + 3);
    CORNERS(0, tt + 2);
    STAGEA(tt + 2, Ab0);
    mfma_phase(Ab1, Bb1, lane, wm, wn, acc);
    COMBINE(0, tt + 2, Bb0);
    __syncthreads();
  }
#undef IDXLOAD
#undef CORNERS
#undef STAGEA
#undef COMBINE

  // epilogue: C write + BN partial sums
  #pragma unroll
  for (int mi = 0; mi < 4; ++mi){
    int obase = wm * 64 + mi * 16 + ((lane >> 4) << 2);
    #pragma unroll
    for (int ni = 0; ni < 4; ++ni){
      int hw = hw0 + wn * 64 + ni * 16 + (lane & 15);
      float* op = out + ((size_t)b * Oout + obase) * HWs + hw;
      #pragma unroll
      for (int r = 0; r < 4; ++r) op[(size_t)r * HWs] = acc[mi][ni][r];
    }
  }
  #pragma unroll
  for (int mi = 0; mi < 4; ++mi){
    #pragma unroll
    for (int r = 0; r < 4; ++r){
      float s = 0.f, s2 = 0.f;
      #pragma unroll
      for (int ni = 0; ni < 4; ++ni){ float v = acc[mi][ni][r]; s += v; s2 += v * v; }
      #pragma unroll
      for (int off2 = 1; off2 < 16; off2 <<= 1){
        s  += __shfl_xor(s, off2);
        s2 += __shfl_xor(s2, off2);
      }
      if ((lane & 15) == 0){
        int o = wm * 64 + mi * 16 + ((lane >> 4) << 2) + r;
        int row = blkm * 2 + wn;                 // 0..1023
        partials[(size_t)row * 256 + o] = s;
        partials[(size_t)1024 * 256 + (size_t)row * 256 + o] = s2;
      }
    }
  }
}

// ---------------- BN stats from partials ----------------
__global__ __launch_bounds__(256) void k_bnstats(const float* __restrict__ partials,
                                                 float* __restrict__ stats){
  int o = blockIdx.x, t = threadIdx.x;
  float s = 0.f, s2 = 0.f;
  for (int i = t; i < 1024; i += 256){
    s  += partials[(size_t)i * 256 + o];
    s2 += partials[(size_t)1024 * 256 + (size_t)i * 256 + o];
  }
  #pragma unroll
  for (int off = 32; off > 0; off >>= 1){
    s  += __shfl_down(s, off);
    s2 += __shfl_down(s2, off);
  }
  __shared__ float rs[4], rs2[4];
  int lane = t & 63, w = t >> 6;
  if (lane == 0){ rs[w] = s; rs2[w] = s2; }
  __syncthreads();
  if (t == 0){
    float S = 0.f, S2 = 0.f;
    for (int i = 0; i < 4; ++i){ S += rs[i]; S2 += rs2[i]; }
    float mean = S / 32768.f;
    float var  = S2 / 32768.f - mean * mean;
    stats[o] = mean;
    stats[256 + o] = rsqrtf(var + 1e-5f);
  }
}

// ---------------- normalize + ReLU in place ----------------
__global__ __launch_bounds__(256) void k_bnapply(float* __restrict__ out,
                                                 const float* __restrict__ stats,
                                                 const float* __restrict__ gamma,
                                                 const float* __restrict__ beta){
  size_t e = ((size_t)blockIdx.x * 256 + threadIdx.x) * 4;
  int o = (int)((e >> 14) & 255);
  float mean = stats[o], rstd = stats[256 + o];
  float sc = rstd * gamma[o];
  float sh = beta[o] - mean * sc;
  float4 v = *(float4*)(out + e);
  v.x = fmaxf(v.x * sc + sh, 0.f);
  v.y = fmaxf(v.y * sc + sh, 0.f);
  v.z = fmaxf(v.z * sc + sh, 0.f);
  v.w = fmaxf(v.w * sc + sh, 0.f);
  *(float4*)(out + e) = v;
}

extern "C" void kernel_launch(void* const* d_in, const int* in_sizes, int n_in,
                              void* d_out, int out_size, void* d_ws, size_t ws_size,
                              hipStream_t stream){
  const float* x     = (const float*)d_in[0];
  const float* w_off = (const float*)d_in[1];
  const float* b_off = (const float*)d_in[2];
  const float* w     = (const float*)d_in[3];
  const float* gamma = (const float*)d_in[4];
  const float* beta  = (const float*)d_in[5];
  float* out = (float*)d_out;

  char* p = (char*)d_ws;
  ushort* xtp  = (ushort*)p; p += (size_t)Bb * PHW * Cin * 2;     // 17.31 MB
  ushort* w2   = (ushort*)p; p += (size_t)Oout * CKd * 2;         // 1.18 MB
  ushort* w2of = (ushort*)p; p += (size_t)32 * CKd * 2;           // 0.15 MB
  int4*   pidx = (int4*)p;   p += (size_t)Bb * 9 * HWs * 16;      // 4.72 MB
  float4* pwt  = (float4*)p; p += (size_t)Bb * 9 * HWs * 16;      // 4.72 MB
  float*  parts= (float*)p;  p += (size_t)2 * 1024 * 256 * 4;     // 2.10 MB
  float*  stats= (float*)p;                                       // 2 KB

  k_transpose<<<dim3(2048), dim3(256), 0, stream>>>(x, xtp);
  k_border   <<<dim3(1032), dim3(64),  0, stream>>>(xtp);
  k_wprep    <<<dim3(2592), dim3(256), 0, stream>>>(w, w_off, w2, w2of);
  k_offconv  <<<dim3(256),  dim3(512), 0, stream>>>(xtp, w2of, b_off, pidx, pwt);
  k_main     <<<dim3(256),  dim3(512), 0, stream>>>(xtp, w2, pidx, pwt, out, parts);
  k_bnstats  <<<dim3(256),  dim3(256), 0, stream>>>(parts, stats);
  k_bnapply  <<<dim3(8192), dim3(256), 0, stream>>>(out, stats, gamma, beta);
}